// Round 11
// baseline (304.474 us; speedup 1.0000x reference)
//
#include <hip/hip_runtime.h>

// PASSED with absmax = 0.0 (bitwise match vs np reference).
// FROZEN: all fp arithmetic (per-element gemm fmaf chain, k ascending;
// attn per-edge ops and per-(dst,channel) ascending-edge-id summation).
// Integer/layout/scheduling changes only.
// R10: (1) REVERT srcs prefetch (cost occupancy, +2us). (2) KV layout
// channel-interleaved: row slot c = [k2c,k2c+1,v2c,v2c+1] so attn loads one
// dwordx4 per edge per lane (2x bytes-in-flight, one 1KB burst per edge).
// gemm K/V stores become strided float2 pairs (store-side, latency-tolerant).

#define FMA4(acc, s, b) do { \
    (acc).x = fmaf((s), (b).x, (acc).x); \
    (acc).y = fmaf((s), (b).y, (acc).y); \
    (acc).z = fmaf((s), (b).z, (acc).z); \
    (acc).w = fmaf((s), (b).w, (acc).w); } while (0)

// ---------------------------------------------------------------------------
// fp32 GEMM, 128x128 tile per block, 8x8 per thread, K in 4 chunks of 32.
// which=0 -> Qf[n][128]; which=1 -> K lanes of KV; which=2 -> V lanes of KV.
// Thread owns rows tr*8..+7, float4-cols {tc, tc+16}. Per-output-element
// arithmetic: single accumulator, fmaf, k=0..127 ascending. FROZEN.
// Hl physical layout XOR-swizzled: phys = row*8 + (k4 ^ ((row>>3)&7)).
// ---------------------------------------------------------------------------
__global__ __launch_bounds__(256) void gemm_qkv(
    const float* __restrict__ h,
    const float* __restrict__ WQ,
    const float* __restrict__ WK,
    const float* __restrict__ WV,
    float* __restrict__ Qf,
    float* __restrict__ KV,
    int N)
{
    __shared__ float4 Wl[32 * 32];   // [k][c4]            16 KB
    __shared__ float4 Hl[128 * 8];   // [row][k4] swizzled 16 KB
    const int t = threadIdx.x;
    const int which = blockIdx.y;
    const float* Wsel = (which == 0) ? WQ : ((which == 1) ? WK : WV);
    const float4* W4 = (const float4*)Wsel;
    const int r0 = blockIdx.x * 128;

    const int tc = t & 15;   // float4 cols tc and tc+16
    const int tr = t >> 4;   // rows tr*8 .. tr*8+7

    float4 acc[8][2];
#pragma unroll
    for (int i = 0; i < 8; ++i) {
        acc[i][0] = make_float4(0.f, 0.f, 0.f, 0.f);
        acc[i][1] = make_float4(0.f, 0.f, 0.f, 0.f);
    }

    for (int kc = 0; kc < 4; ++kc) {
        __syncthreads();   // protect previous chunk's reads
#pragma unroll
        for (int i = 0; i < 4; ++i) {           // Wl: 32 k-rows x 32 float4
            const int idx = t + i * 256;
            const int k = idx >> 5, c = idx & 31;
            Wl[idx] = W4[(size_t)(kc * 32 + k) * 32 + c];
        }
#pragma unroll
        for (int i = 0; i < 4; ++i) {           // Hl: 128 rows x 8 float4
            const int idx = t + i * 256;
            const int row = idx >> 3, kk = idx & 7;
            float4 v = make_float4(0.f, 0.f, 0.f, 0.f);
            if (r0 + row < N)
                v = ((const float4*)h)[(size_t)(r0 + row) * 32 + kc * 8 + kk];
            Hl[row * 8 + (kk ^ ((row >> 3) & 7))] = v;   // swizzled store
        }
        __syncthreads();

        for (int k4 = 0; k4 < 8; ++k4) {
            const float4 b0a = Wl[(k4 * 4 + 0) * 32 + tc];
            const float4 b0b = Wl[(k4 * 4 + 0) * 32 + tc + 16];
            const float4 b1a = Wl[(k4 * 4 + 1) * 32 + tc];
            const float4 b1b = Wl[(k4 * 4 + 1) * 32 + tc + 16];
            const float4 b2a = Wl[(k4 * 4 + 2) * 32 + tc];
            const float4 b2b = Wl[(k4 * 4 + 2) * 32 + tc + 16];
            const float4 b3a = Wl[(k4 * 4 + 3) * 32 + tc];
            const float4 b3b = Wl[(k4 * 4 + 3) * 32 + tc + 16];
#pragma unroll
            for (int r = 0; r < 8; ++r) {
                const int row = tr * 8 + r;
                const float4 a = Hl[row * 8 + (k4 ^ (tr & 7))];  // swizzled read
                // per-element k order: kk = 0,1,2,3 (a.x,a.y,a.z,a.w)
                FMA4(acc[r][0], a.x, b0a); FMA4(acc[r][1], a.x, b0b);
                FMA4(acc[r][0], a.y, b1a); FMA4(acc[r][1], a.y, b1b);
                FMA4(acc[r][0], a.z, b2a); FMA4(acc[r][1], a.z, b2b);
                FMA4(acc[r][0], a.w, b3a); FMA4(acc[r][1], a.w, b3b);
            }
        }
    }

    if (which == 0) {
        float4* O = (float4*)Qf;
#pragma unroll
        for (int r = 0; r < 8; ++r) {
            const int row = r0 + tr * 8 + r;
            if (row < N) {
                O[(size_t)row * 32 + tc]      = acc[r][0];
                O[(size_t)row * 32 + tc + 16] = acc[r][1];
            }
        }
    } else {
        // Interleaved KV row: 128 float2 half-slots; slot c (float4) =
        // [k_{2c},k_{2c+1} | v_{2c},v_{2c+1}]. K writes lo halves (+0),
        // V writes hi halves (+1).
        float2* O2 = (float2*)KV;
        const int voff = (which == 2) ? 1 : 0;
#pragma unroll
        for (int r = 0; r < 8; ++r) {
            const int row = r0 + tr * 8 + r;
            if (row < N) {
                const size_t base = (size_t)row * 128;
                O2[base + 4 * tc + 0 + voff]  = make_float2(acc[r][0].x, acc[r][0].y);
                O2[base + 4 * tc + 2 + voff]  = make_float2(acc[r][0].z, acc[r][0].w);
                O2[base + 4 * tc + 64 + voff] = make_float2(acc[r][1].x, acc[r][1].y);
                O2[base + 4 * tc + 66 + voff] = make_float2(acc[r][1].z, acc[r][1].w);
            }
        }
    }
}

// -------------------------- CSR build (stable by dst) ----------------------
__global__ __launch_bounds__(256) void count_deg(
    const int* __restrict__ dst, int* __restrict__ deg, int E)
{
    const int e = blockIdx.x * 256 + threadIdx.x;
    if (e < E) atomicAdd(&deg[dst[e]], 1);
}

__global__ __launch_bounds__(256) void chunk_reduce(
    const int* __restrict__ deg, int* __restrict__ csum, int N)
{
    const int t = threadIdx.x;
    const int i = blockIdx.x * 256 + t;
    int x = (i < N) ? deg[i] : 0;
#pragma unroll
    for (int off = 32; off; off >>= 1) x += __shfl_down(x, off, 64);
    __shared__ int ws[4];
    if ((t & 63) == 0) ws[t >> 6] = x;
    __syncthreads();
    if (t == 0) csum[blockIdx.x] = ws[0] + ws[1] + ws[2] + ws[3];
}

__global__ __launch_bounds__(256) void scan_chunks(
    const int* __restrict__ csum, int* __restrict__ coff, int nChunks)
{
    __shared__ int s[256];
    __shared__ int carry;
    const int t = threadIdx.x;
    if (t == 0) carry = 0;
    __syncthreads();
    for (int base = 0; base < nChunks; base += 256) {
        const int i = base + t;
        int x = (i < nChunks) ? csum[i] : 0;
        s[t] = x;
        __syncthreads();
        for (int off = 1; off < 256; off <<= 1) {
            int v = (t >= off) ? s[t - off] : 0;
            __syncthreads();
            s[t] += v;
            __syncthreads();
        }
        if (i < nChunks) coff[i] = carry + s[t] - x;  // exclusive
        __syncthreads();
        if (t == 0) carry += s[255];
        __syncthreads();
    }
}

__global__ __launch_bounds__(256) void chunk_scan(
    const int* __restrict__ deg, const int* __restrict__ coff,
    int* __restrict__ rowptr, int N)
{
    __shared__ int s[256];
    const int t = threadIdx.x;
    const int i = blockIdx.x * 256 + t;
    int x = (i < N) ? deg[i] : 0;
    s[t] = x;
    __syncthreads();
    for (int off = 1; off < 256; off <<= 1) {
        int v = (t >= off) ? s[t - off] : 0;
        __syncthreads();
        s[t] += v;
        __syncthreads();
    }
    if (i < N) rowptr[i + 1] = coff[blockIdx.x] + s[t];
    if (i == 0) rowptr[0] = 0;
}

// Scatter eids via atomic ticket (arrival order; rank fixes it).
__global__ __launch_bounds__(256) void scatter_eids(
    const int* __restrict__ dst, const int* __restrict__ rowptr,
    int* __restrict__ cur, int* __restrict__ eids, int E)
{
    const int e = blockIdx.x * 256 + threadIdx.x;
    if (e >= E) return;
    const int d = dst[e];
    const int pos = rowptr[d] + atomicAdd(&cur[d], 1);
    eids[pos] = e;
}

// Wave-parallel stable ordering: rank(e) = #{e' in same dst : eid' < eid}.
// One wave per dst. srcs[lo+rank] = src[eid] -> ascending-eid order ==
// np.add.at order. deg > 64 serial fallback (P ~ 0 for Poisson(16)).
__global__ __launch_bounds__(256) void rank_emit(
    const int* __restrict__ rowptr, const int* __restrict__ eids,
    const int* __restrict__ src, int* __restrict__ srcs, int N)
{
    const int wave = threadIdx.x >> 6;
    const int lane = threadIdx.x & 63;
    const int d = blockIdx.x * 4 + wave;
    if (d >= N) return;
    const int lo = rowptr[d];
    const int deg = rowptr[d + 1] - lo;
    if (deg <= 64) {
        int p = 0x7fffffff;
        if (lane < deg) p = eids[lo + lane];
        int rank = 0;
        for (int j = 0; j < deg; ++j) {
            const int kj = __shfl(p, j, 64);
            rank += (kj < p) ? 1 : 0;
        }
        if (lane < deg) srcs[lo + rank] = src[p];
    } else if (lane == 0) {
        for (int i = 0; i < deg; ++i) {
            const int pi = eids[lo + i];
            int rank = 0;
            for (int j = 0; j < deg; ++j) rank += (eids[lo + j] < pi) ? 1 : 0;
            srcs[lo + rank] = src[pi];
        }
    }
}

// ------------------- np.add.at-order fp32 edge accumulation ----------------
// FROZEN per channel: sc = (k*q)*0.25f; z += sc; wv += v*sc, edges ascending.
// One wave per dst (2 waves/block); lane owns channels {2c,2c+1}; per edge ONE
// dwordx4 [k2c,k2c+1,v2c,v2c+1]; unroll-8 = 8KB in flight per wave.
__global__ __launch_bounds__(128) void attn_out(
    const int* __restrict__ srcs, const int* __restrict__ rowptr,
    const float* __restrict__ KV, const float* __restrict__ Qf,
    float* __restrict__ out, int N)
{
#pragma clang fp contract(off)
    const int wave = threadIdx.x >> 6;
    const int lane = threadIdx.x & 63;
    const int d = blockIdx.x * 2 + wave;
    if (d >= N) return;
    const float2 q = ((const float2*)Qf)[(size_t)d * 64 + lane];
    const int lo = rowptr[d], hi = rowptr[d + 1];
    const float4* KV4 = (const float4*)KV;
    float2 z = make_float2(0.f, 0.f), wv = z;

#define EDGE_UPD(kv) do { \
        float sc0 = ((kv).x * q.x) * 0.25f; z.x = z.x + sc0; wv.x = wv.x + (kv).z * sc0; \
        float sc1 = ((kv).y * q.y) * 0.25f; z.y = z.y + sc1; wv.y = wv.y + (kv).w * sc1; \
    } while (0)

    int i = lo;
    for (; i + 8 <= hi; i += 8) {
        int s[8];
#pragma unroll
        for (int u = 0; u < 8; ++u) s[u] = srcs[i + u];
        float4 kv[8];
#pragma unroll
        for (int u = 0; u < 8; ++u) kv[u] = KV4[(size_t)s[u] * 64 + lane];
#pragma unroll
        for (int u = 0; u < 8; ++u) EDGE_UPD(kv[u]);
    }
    for (; i + 4 <= hi; i += 4) {
        const int s0 = srcs[i + 0], s1 = srcs[i + 1];
        const int s2 = srcs[i + 2], s3 = srcs[i + 3];
        const float4 kv0 = KV4[(size_t)s0 * 64 + lane];
        const float4 kv1 = KV4[(size_t)s1 * 64 + lane];
        const float4 kv2 = KV4[(size_t)s2 * 64 + lane];
        const float4 kv3 = KV4[(size_t)s3 * 64 + lane];
        EDGE_UPD(kv0); EDGE_UPD(kv1); EDGE_UPD(kv2); EDGE_UPD(kv3);
    }
    for (; i < hi; ++i) {
        const float4 kv = KV4[(size_t)srcs[i] * 64 + lane];
        EDGE_UPD(kv);
    }
#undef EDGE_UPD

    float2 o;
    o.x = wv.x / (z.x + 1e-6f);
    o.y = wv.y / (z.y + 1e-6f);
    ((float2*)out)[(size_t)d * 64 + lane] = o;
}

extern "C" void kernel_launch(void* const* d_in, const int* in_sizes, int n_in,
                              void* d_out, int out_size, void* d_ws, size_t ws_size,
                              hipStream_t stream)
{
    const float* h  = (const float*)d_in[0];
    const int* src  = (const int*)d_in[1];
    const int* dst  = (const int*)d_in[2];
    const float* WQ = (const float*)d_in[3];
    const float* WK = (const float*)d_in[4];
    const float* WV = (const float*)d_in[5];
    const int N = in_sizes[0] / 128;   // 40000
    const int E = in_sizes[1];         // 640000
    const size_t NC = (size_t)N * 128;
    const int nChunks = (N + 255) / 256;

    // Workspace (~75 MB).
    float* KV = (float*)d_ws;          // N*256 f32, channel-interleaved K|V
    float* Qf = KV + (size_t)N * 256;  // N*128 f32
    int* deg    = (int*)(Qf + NC);     // N
    int* cur    = deg + N;             // N
    int* rowptr = cur + N;             // N+1
    int* csum   = rowptr + (N + 1);    // nChunks
    int* coff   = csum + nChunks;      // nChunks
    int* srcs   = coff + nChunks;      // E
    int* eids   = srcs + E;            // E
    float* outp = (float*)d_out;

    hipMemsetAsync(deg, 0, (size_t)2 * N * sizeof(int), stream);  // deg + cur

    dim3 ggrid((N + 127) / 128, 3);
    gemm_qkv<<<ggrid, 256, 0, stream>>>(h, WQ, WK, WV, Qf, KV, N);

    const int eb = (E + 255) / 256;
    count_deg<<<eb, 256, 0, stream>>>(dst, deg, E);
    chunk_reduce<<<nChunks, 256, 0, stream>>>(deg, csum, N);
    scan_chunks<<<1, 256, 0, stream>>>(csum, coff, nChunks);
    chunk_scan<<<nChunks, 256, 0, stream>>>(deg, coff, rowptr, N);
    scatter_eids<<<eb, 256, 0, stream>>>(dst, rowptr, cur, eids, E);
    rank_emit<<<(N + 3) / 4, 256, 0, stream>>>(rowptr, eids, src, srcs, N);

    attn_out<<<(N + 1) / 2, 128, 0, stream>>>(srcs, rowptr, KV, Qf, outp, N);
}